// Round 1
// baseline (172.952 us; speedup 1.0000x reference)
//
#include <hip/hip_runtime.h>
#include <hip/hip_bf16.h>

// Dims fixed by the reference setup.
#define T_DIM 128
#define S_DIM 128
#define B_DIM 32
#define H_DIM 512
#define C_DIM 512
#define M_DIM 256
#define NEG_BIG -1e8f

// tanh(x) = 1 - 2/(exp(2x)+1); exp via v_exp_f32, div via v_rcp_f32.
// Saturates correctly: x->+inf => exp2->inf => rcp->0 => 1; x->-inf => exp2->0 => rcp(1)=1 => -1.
__device__ __forceinline__ float tanh_fast(float x) {
  float e = __builtin_amdgcn_exp2f(2.885390082f * x);   // exp(2x)
  return 1.f - 2.f * __builtin_amdgcn_rcpf(e + 1.f);
}

// ---------------------------------------------------------------------------
// Generic f32 GEMM: Y[n][m] = sum_k X[n][k] * W[m][k]
// Block: 64x64 tile, 256 threads, 4x4 micro-tile. K staged in LDS transposed
// ([BK][BN+4]) so fragment reads are float4 (ds_read_b128, conflict-free).
// ---------------------------------------------------------------------------
__global__ __launch_bounds__(256) void gemm_xwt_f32(
    const float* __restrict__ X, const float* __restrict__ W,
    float* __restrict__ Y, int N, int K, int Mo) {
  __shared__ float Xs[16][68];
  __shared__ float Ws[16][68];
  const int tid = threadIdx.x;
  const int tx = tid & 15;       // m micro-tile
  const int ty = tid >> 4;       // n micro-tile
  const int n0 = blockIdx.y * 64;
  const int m0 = blockIdx.x * 64;
  const int lr = tid >> 2;          // 0..63 load row
  const int lk = (tid & 3) << 2;    // k quad within 16-chunk
  float acc[4][4] = {{0.f, 0.f, 0.f, 0.f}};

  for (int k0 = 0; k0 < K; k0 += 16) {
    float4 xv = *(const float4*)(X + (size_t)(n0 + lr) * K + (k0 + lk));
    float4 wv = *(const float4*)(W + (size_t)(m0 + lr) * K + (k0 + lk));
    __syncthreads();
    Xs[lk + 0][lr] = xv.x; Xs[lk + 1][lr] = xv.y; Xs[lk + 2][lr] = xv.z; Xs[lk + 3][lr] = xv.w;
    Ws[lk + 0][lr] = wv.x; Ws[lk + 1][lr] = wv.y; Ws[lk + 2][lr] = wv.z; Ws[lk + 3][lr] = wv.w;
    __syncthreads();
#pragma unroll
    for (int kk = 0; kk < 16; ++kk) {
      const float4 a4 = *(const float4*)(&Xs[kk][ty << 2]);
      const float4 b4 = *(const float4*)(&Ws[kk][tx << 2]);
      const float ar[4] = {a4.x, a4.y, a4.z, a4.w};
      const float br[4] = {b4.x, b4.y, b4.z, b4.w};
#pragma unroll
      for (int i = 0; i < 4; ++i)
#pragma unroll
        for (int j = 0; j < 4; ++j) acc[i][j] += ar[i] * br[j];
    }
  }
#pragma unroll
  for (int i = 0; i < 4; ++i) {
    float4 o = make_float4(acc[i][0], acc[i][1], acc[i][2], acc[i][3]);
    *(float4*)(Y + (size_t)(n0 + (ty << 2) + i) * Mo + m0 + (tx << 2)) = o;
  }
}

// ---------------------------------------------------------------------------
// Fused scores + softmax.
// Block: fixed b, 8 t-rows. scores[s][t] = sum_m tanh(hid_m[t,b,m]+ctx_m[s,b,m])*w_ff[m]
// then softmax over s (S=128). Writes alpha to out (T,S,B layout, the actual
// output) and a b-major copy to ws for coalesced reads in attend_kernel.
// ---------------------------------------------------------------------------
__global__ __launch_bounds__(256) void scores_softmax_kernel(
    const float* __restrict__ hid_m, const float* __restrict__ ctx_m,
    const float* __restrict__ w_ff, const float* __restrict__ ctx_mask,
    float* __restrict__ alpha_out, float* __restrict__ alpha_ws) {
  __shared__ float4 h4[8][65];     // hid_m tile, 8 t-rows x 64 quads (+pad)
  __shared__ float4 c4[32][65];    // ctx_m chunk, 32 s-rows
  __shared__ float4 wf4[64];
  __shared__ float msk[S_DIM];
  __shared__ float sc[8][129];     // scores [t][s]
  const int tid = threadIdx.x;
  const int b = blockIdx.y;
  const int t0 = blockIdx.x << 3;

  for (int i = tid; i < 8 * 64; i += 256) {
    int r = i >> 6, q = i & 63;
    h4[r][q] = *(const float4*)(hid_m + ((size_t)(t0 + r) * B_DIM + b) * M_DIM + (q << 2));
  }
  if (tid < 64) wf4[tid] = *(const float4*)(w_ff + (tid << 2));
  if (tid < S_DIM) msk[tid] = ctx_mask[(size_t)tid * B_DIM + b];

  const int tt = tid >> 5;   // 0..7
  const int ss = tid & 31;   // 0..31

  for (int s0 = 0; s0 < S_DIM; s0 += 32) {
    __syncthreads();  // previous chunk's readers done (also covers h4/wf4/msk staging)
    for (int i = tid; i < 32 * 64; i += 256) {
      int r = i >> 6, q = i & 63;
      c4[r][q] = *(const float4*)(ctx_m + ((size_t)(s0 + r) * B_DIM + b) * M_DIM + (q << 2));
    }
    __syncthreads();
    float acc = 0.f;
#pragma unroll 8
    for (int q = 0; q < 64; ++q) {
      const float4 h = h4[tt][q];
      const float4 c = c4[ss][q];
      const float4 w = wf4[q];
      acc += tanh_fast(h.x + c.x) * w.x;
      acc += tanh_fast(h.y + c.y) * w.y;
      acc += tanh_fast(h.z + c.z) * w.z;
      acc += tanh_fast(h.w + c.w) * w.w;
    }
    const int s = s0 + ss;
    sc[tt][s] = (msk[s] > 0.f) ? acc : NEG_BIG;   // TEMP == 1.0
  }
  __syncthreads();

  // Softmax over s per t-row; 32 lanes cooperate per row (4 s each).
  const int j = ss;
  const float v0 = sc[tt][j], v1 = sc[tt][j + 32], v2 = sc[tt][j + 64], v3 = sc[tt][j + 96];
  float mx = fmaxf(fmaxf(v0, v1), fmaxf(v2, v3));
#pragma unroll
  for (int off = 16; off > 0; off >>= 1) mx = fmaxf(mx, __shfl_xor(mx, off));
  const float e0 = __expf(v0 - mx), e1 = __expf(v1 - mx), e2 = __expf(v2 - mx), e3 = __expf(v3 - mx);
  float sum = e0 + e1 + e2 + e3;
#pragma unroll
  for (int off = 16; off > 0; off >>= 1) sum += __shfl_xor(sum, off);
  const float rinv = 1.f / sum;
  const int t = t0 + tt;
  float* ao = alpha_out + (size_t)t * (S_DIM * B_DIM) + b;
  ao[(j) * B_DIM] = e0 * rinv;
  ao[(j + 32) * B_DIM] = e1 * rinv;
  ao[(j + 64) * B_DIM] = e2 * rinv;
  ao[(j + 96) * B_DIM] = e3 * rinv;
  float* aw = alpha_ws + ((size_t)b * T_DIM + t) * S_DIM;
  aw[j] = e0 * rinv;
  aw[j + 32] = e1 * rinv;
  aw[j + 64] = e2 * rinv;
  aw[j + 96] = e3 * rinv;
}

// ---------------------------------------------------------------------------
// attended[t][b][c] = sum_s alpha[b][t][s] * ctx[s][b][c]
// Block: fixed b, 16 t-rows. Each thread owns (tt, 8 interleaved float4 cols),
// accumulates in registers over all S, bounces through LDS for coalesced store.
// ---------------------------------------------------------------------------
__global__ __launch_bounds__(256) void attend_kernel(
    const float* __restrict__ alpha_ws, const float* __restrict__ ctx,
    float* __restrict__ att) {
  __shared__ float al[16][129];
  __shared__ float4 cx4[8][129];
  __shared__ float4 a4[16][129];
  const int tid = threadIdx.x;
  const int b = blockIdx.y;
  const int t0 = blockIdx.x << 4;

  for (int i = tid; i < 16 * 128; i += 256) {
    int r = i >> 7, s = i & 127;
    al[r][s] = alpha_ws[((size_t)b * T_DIM + t0 + r) * S_DIM + s];
  }
  const int tt = tid >> 4;   // 0..15 t-row
  const int cg = tid & 15;   // col group
  float4 acc[8];
#pragma unroll
  for (int jj = 0; jj < 8; ++jj) acc[jj] = make_float4(0.f, 0.f, 0.f, 0.f);

  for (int s0 = 0; s0 < S_DIM; s0 += 8) {
    __syncthreads();
    for (int i = tid; i < 8 * 128; i += 256) {
      int r = i >> 7, q = i & 127;
      cx4[r][q] = *(const float4*)(ctx + ((size_t)(s0 + r) * B_DIM + b) * C_DIM + (q << 2));
    }
    __syncthreads();
#pragma unroll
    for (int r = 0; r < 8; ++r) {
      const float a = al[tt][s0 + r];
#pragma unroll
      for (int jj = 0; jj < 8; ++jj) {
        const float4 c = cx4[r][cg + (jj << 4)];
        acc[jj].x += a * c.x; acc[jj].y += a * c.y;
        acc[jj].z += a * c.z; acc[jj].w += a * c.w;
      }
    }
  }
  __syncthreads();
#pragma unroll
  for (int jj = 0; jj < 8; ++jj) a4[tt][cg + (jj << 4)] = acc[jj];
  __syncthreads();
  for (int i = tid; i < 16 * 128; i += 256) {
    int r = i >> 7, q = i & 127;
    *(float4*)(att + ((size_t)(t0 + r) * B_DIM + b) * C_DIM + (q << 2)) = a4[r][q];
  }
}

// ---------------------------------------------------------------------------
extern "C" void kernel_launch(void* const* d_in, const int* in_sizes, int n_in,
                              void* d_out, int out_size, void* d_ws, size_t ws_size,
                              hipStream_t stream) {
  const float* hid       = (const float*)d_in[0];   // (T,B,H)
  const float* ctx       = (const float*)d_in[1];   // (S,B,C)
  const float* ctx_mask  = (const float*)d_in[2];   // (S,B)
  const float* W_hid2mid = (const float*)d_in[3];   // (M,H)
  const float* W_ctx2mid = (const float*)d_in[4];   // (M,C)
  const float* w_ff      = (const float*)d_in[5];   // (M,)
  const float* W_att2hid = (const float*)d_in[6];   // (H,C)
  float* out = (float*)d_out;
  float* ws  = (float*)d_ws;

  // ws layout (floats): [0,1M) hid_m | [1M,2M) ctx_m | [2M,4M) att | [4M,4.5M) alpha_ws
  float* hid_m    = ws;
  float* ctx_m    = ws + (1u << 20);
  float* att      = ws + (2u << 20);
  float* alpha_ws = ws + (4u << 20);
  float* alpha_out = out;                              // (T,S,B)
  float* z_out     = out + T_DIM * S_DIM * B_DIM;      // (T,B,H)

  dim3 blk(256);
  // hid_m (T,B,M) = hid (4096x512) . W_hid2mid^T
  gemm_xwt_f32<<<dim3(M_DIM / 64, (T_DIM * B_DIM) / 64), blk, 0, stream>>>(
      hid, W_hid2mid, hid_m, T_DIM * B_DIM, H_DIM, M_DIM);
  // ctx_m (S,B,M) = ctx (4096x512) . W_ctx2mid^T
  gemm_xwt_f32<<<dim3(M_DIM / 64, (S_DIM * B_DIM) / 64), blk, 0, stream>>>(
      ctx, W_ctx2mid, ctx_m, S_DIM * B_DIM, C_DIM, M_DIM);
  // fused tanh-scores + masked softmax -> alpha
  scores_softmax_kernel<<<dim3(T_DIM / 8, B_DIM), blk, 0, stream>>>(
      hid_m, ctx_m, w_ff, ctx_mask, alpha_out, alpha_ws);
  // attended (T,B,C)
  attend_kernel<<<dim3(T_DIM / 16, B_DIM), blk, 0, stream>>>(alpha_ws, ctx, att);
  // z (T,B,H) = att (4096x512) . W_att2hid^T
  gemm_xwt_f32<<<dim3(H_DIM / 64, (T_DIM * B_DIM) / 64), blk, 0, stream>>>(
      att, W_att2hid, z_out, T_DIM * B_DIM, C_DIM, H_DIM);
}

// Round 2
// 97.500 us; speedup vs baseline: 1.7739x; 1.7739x over previous
//
#include <hip/hip_runtime.h>
#include <hip/hip_bf16.h>

#define T_DIM 128
#define S_DIM 128
#define B_DIM 32
#define H_DIM 512
#define C_DIM 512
#define M_DIM 256
#define NEG_BIG -1e8f
#define K2LOG2E 2.8853900817779268f   // 2*log2(e): exp(2x) = exp2(K*x)

typedef __attribute__((ext_vector_type(8))) short shortx8;   // 8 bf16
typedef __attribute__((ext_vector_type(4))) float floatx4;

// f32 -> bf16 RNE, packed pair
__device__ __forceinline__ unsigned bfpair(float a, float b) {
  unsigned ua = __builtin_bit_cast(unsigned, a); ua += 0x7fffu + ((ua >> 16) & 1u);
  unsigned ub = __builtin_bit_cast(unsigned, b); ub += 0x7fffu + ((ub >> 16) & 1u);
  return (ua >> 16) | (ub & 0xffff0000u);
}

// ---------------------------------------------------------------------------
// Pre-convert 5 f32 regions to bf16 (grouped by 8 elements per thread).
// ---------------------------------------------------------------------------
__device__ __forceinline__ void cvt8(const float* __restrict__ s,
                                     ushort* __restrict__ d, int g) {
  const float4 x = *(const float4*)(s + (size_t)g * 8);
  const float4 y = *(const float4*)(s + (size_t)g * 8 + 4);
  uint4 o;
  o.x = bfpair(x.x, x.y); o.y = bfpair(x.z, x.w);
  o.z = bfpair(y.x, y.y); o.w = bfpair(y.z, y.w);
  *(uint4*)(d + (size_t)g * 8) = o;
}

__global__ __launch_bounds__(256) void cvt_kernel(
    const float* a0, ushort* b0, int c0, const float* a1, ushort* b1, int c1,
    const float* a2, ushort* b2, int c2, const float* a3, ushort* b3, int c3,
    const float* a4, ushort* b4, int c4) {
  int g = blockIdx.x * 256 + threadIdx.x;
  if (g < c0) { cvt8(a0, b0, g); return; } g -= c0;
  if (g < c1) { cvt8(a1, b1, g); return; } g -= c1;
  if (g < c2) { cvt8(a2, b2, g); return; } g -= c2;
  if (g < c3) { cvt8(a3, b3, g); return; } g -= c3;
  if (g < c4) { cvt8(a4, b4, g); }
}

// ---------------------------------------------------------------------------
// MFMA bf16 GEMM: Y[n][m] = sum_k X[n][k]*W[m][k], f32 out.
// EXPOUT: Y = exp2(K2LOG2E * acc) for the exp-factored tanh trick.
// 64x64 tile, BK=64, 4 waves (2x2), each wave 32x32 = 2x2 frags of 16x16x32.
// LDS XOR-swizzled (slot ^= row&7) so frag ds_read_b128 is ~2-way (free).
// ---------------------------------------------------------------------------
template <int EXPOUT>
__global__ __launch_bounds__(256) void gemm_bf16_mfma(
    const ushort* __restrict__ X, const ushort* __restrict__ W,
    float* __restrict__ Y, int N, int K, int Mo) {
  __shared__ ushort Xs[64 * 64];
  __shared__ ushort Ws[64 * 64];
  const int tid = threadIdx.x;
  const int n0 = blockIdx.y * 64, m0 = blockIdx.x * 64;
  const int lane = tid & 63, wave = tid >> 6;
  const int wn = wave & 1, wm = wave >> 1;
  const int l15 = lane & 15, lhi = lane >> 4;
  floatx4 acc[2][2];
#pragma unroll
  for (int i = 0; i < 2; ++i)
#pragma unroll
    for (int j = 0; j < 2; ++j) acc[i][j] = (floatx4){0.f, 0.f, 0.f, 0.f};

  const int r0 = tid >> 3, s0 = tid & 7;            // load slot 0
  const int r1 = (tid + 256) >> 3, s1 = tid & 7;    // load slot 1

  for (int k0 = 0; k0 < K; k0 += 64) {
    uint4 xa = *(const uint4*)(X + (size_t)(n0 + r0) * K + k0 + s0 * 8);
    uint4 wa = *(const uint4*)(W + (size_t)(m0 + r0) * K + k0 + s0 * 8);
    uint4 xb = *(const uint4*)(X + (size_t)(n0 + r1) * K + k0 + s1 * 8);
    uint4 wb = *(const uint4*)(W + (size_t)(m0 + r1) * K + k0 + s1 * 8);
    __syncthreads();
    *(uint4*)((char*)Xs + r0 * 128 + ((s0 ^ (r0 & 7)) << 4)) = xa;
    *(uint4*)((char*)Ws + r0 * 128 + ((s0 ^ (r0 & 7)) << 4)) = wa;
    *(uint4*)((char*)Xs + r1 * 128 + ((s1 ^ (r1 & 7)) << 4)) = xb;
    *(uint4*)((char*)Ws + r1 * 128 + ((s1 ^ (r1 & 7)) << 4)) = wb;
    __syncthreads();
#pragma unroll
    for (int ks = 0; ks < 2; ++ks) {
      const int slot = lhi + ks * 4;
      shortx8 af[2], bf[2];
#pragma unroll
      for (int fi = 0; fi < 2; ++fi) {
        const int row = wn * 32 + fi * 16 + l15;
        af[fi] = *(const shortx8*)((const char*)Xs + row * 128 + ((slot ^ (row & 7)) << 4));
      }
#pragma unroll
      for (int fj = 0; fj < 2; ++fj) {
        const int col = wm * 32 + fj * 16 + l15;
        bf[fj] = *(const shortx8*)((const char*)Ws + col * 128 + ((slot ^ (col & 7)) << 4));
      }
#pragma unroll
      for (int fi = 0; fi < 2; ++fi)
#pragma unroll
        for (int fj = 0; fj < 2; ++fj)
          acc[fi][fj] = __builtin_amdgcn_mfma_f32_16x16x32_bf16(af[fi], bf[fj], acc[fi][fj], 0, 0, 0);
    }
  }
#pragma unroll
  for (int fi = 0; fi < 2; ++fi)
#pragma unroll
    for (int fj = 0; fj < 2; ++fj)
#pragma unroll
      for (int r = 0; r < 4; ++r) {
        const int row = n0 + wn * 32 + fi * 16 + lhi * 4 + r;
        const int col = m0 + wm * 32 + fj * 16 + l15;
        float v = acc[fi][fj][r];
        if (EXPOUT) v = __builtin_amdgcn_exp2f(K2LOG2E * v);
        Y[(size_t)row * Mo + col] = v;
      }
}

// ---------------------------------------------------------------------------
// Fused scores + softmax, exp-factored:
//   alpha(s) = softmax_s( -2 * sum_m w[m] * rcp(EH[t,b,m]*EC[s,b,m] + 1) )
// (the Sum(w) constant cancels in softmax). Block: 8 t-rows x full S, fixed b.
// Thread micro-tile 2t x 2s (t = 2tt+{0,1}, s = st+{0,64}). Writes b-major
// alpha_ws (coalesced); (T,S,B) output produced by alpha_tr_kernel.
// ---------------------------------------------------------------------------
__global__ __launch_bounds__(256) void scores_kernel(
    const float* __restrict__ EH, const float* __restrict__ EC,
    const float* __restrict__ w_ff, const float* __restrict__ ctx_mask,
    float* __restrict__ aws) {
  __shared__ float4 ec_t[16][128];   // [m-quad][s], linear: reads conflict-free
  __shared__ float4 eh_t[16][8];     // [m-quad][t] (broadcast reads)
  __shared__ float4 wf[16];
  __shared__ float msk[S_DIM];
  const int tid = threadIdx.x;
  const int b = blockIdx.y;
  const int t0 = blockIdx.x << 3;
  const int tt = tid >> 6;   // 0..3 -> t rows 2tt, 2tt+1
  const int st = tid & 63;   // s = st, st+64

  if (tid < S_DIM) msk[tid] = ctx_mask[(size_t)tid * B_DIM + b];

  floatx4 acc[2][2];
#pragma unroll
  for (int i = 0; i < 2; ++i)
#pragma unroll
    for (int j = 0; j < 2; ++j) acc[i][j] = (floatx4){0.f, 0.f, 0.f, 0.f};

  for (int mc = 0; mc < 4; ++mc) {
    __syncthreads();
#pragma unroll
    for (int i = 0; i < 8; ++i) {
      const int idx = tid + (i << 8);
      const int s = idx >> 4, q = idx & 15;
      ec_t[q][s] = *(const float4*)(EC + ((size_t)s * B_DIM + b) * M_DIM + (mc << 6) + (q << 2));
    }
    if (tid < 128) {
      const int t = tid >> 4, q = tid & 15;
      eh_t[q][t] = *(const float4*)(EH + ((size_t)(t0 + t) * B_DIM + b) * M_DIM + (mc << 6) + (q << 2));
    }
    if (tid < 16) wf[tid] = *(const float4*)(w_ff + (mc << 6) + (tid << 2));
    __syncthreads();
#pragma unroll
    for (int q = 0; q < 16; ++q) {
      const float4 w4 = wf[q];
      const float4 e0 = eh_t[q][2 * tt], e1 = eh_t[q][2 * tt + 1];
      const float4 c0 = ec_t[q][st],     c1 = ec_t[q][st + 64];
#define ACC1(A, E, C)                                                  \
  A[0] += w4.x * __builtin_amdgcn_rcpf(E.x * C.x + 1.f);               \
  A[1] += w4.y * __builtin_amdgcn_rcpf(E.y * C.y + 1.f);               \
  A[2] += w4.z * __builtin_amdgcn_rcpf(E.z * C.z + 1.f);               \
  A[3] += w4.w * __builtin_amdgcn_rcpf(E.w * C.w + 1.f);
      ACC1(acc[0][0], e0, c0) ACC1(acc[0][1], e0, c1)
      ACC1(acc[1][0], e1, c0) ACC1(acc[1][1], e1, c1)
#undef ACC1
    }
  }

  const float mk0 = msk[st], mk1 = msk[st + 64];
  float sc[2][2];
#pragma unroll
  for (int ti = 0; ti < 2; ++ti) {
    const floatx4 a0 = acc[ti][0], a1 = acc[ti][1];
    sc[ti][0] = (mk0 > 0.f) ? -2.f * (a0[0] + a0[1] + a0[2] + a0[3]) : NEG_BIG;
    sc[ti][1] = (mk1 > 0.f) ? -2.f * (a1[0] + a1[1] + a1[2] + a1[3]) : NEG_BIG;
  }
#pragma unroll
  for (int ti = 0; ti < 2; ++ti) {
    float mx = fmaxf(sc[ti][0], sc[ti][1]);
#pragma unroll
    for (int off = 32; off > 0; off >>= 1) mx = fmaxf(mx, __shfl_xor(mx, off));
    const float e0 = __expf(sc[ti][0] - mx), e1 = __expf(sc[ti][1] - mx);
    float sum = e0 + e1;
#pragma unroll
    for (int off = 32; off > 0; off >>= 1) sum += __shfl_xor(sum, off);
    const float rinv = 1.f / sum;
    float* w = aws + ((size_t)b * T_DIM + t0 + 2 * tt + ti) * S_DIM;
    w[st] = e0 * rinv;
    w[st + 64] = e1 * rinv;
  }
}

// ---------------------------------------------------------------------------
// alpha_ws (B,T,S) -> out (T,S,B), 32x32 LDS tiles, both sides coalesced.
// ---------------------------------------------------------------------------
__global__ __launch_bounds__(256) void alpha_tr_kernel(
    const float* __restrict__ aws, float* __restrict__ aout) {
  __shared__ float tile[32][33];
  const int t = blockIdx.x;
  const int s0 = blockIdx.y * 32;
  const int x = threadIdx.x & 31, y = threadIdx.x >> 5;   // y: 0..7
#pragma unroll
  for (int i = 0; i < 4; ++i) {
    const int b_ = i * 8 + y;
    tile[b_][x] = aws[((size_t)b_ * T_DIM + t) * S_DIM + s0 + x];
  }
  __syncthreads();
#pragma unroll
  for (int i = 0; i < 4; ++i) {
    const int s_ = i * 8 + y;
    aout[((size_t)t * S_DIM + s0 + s_) * B_DIM + x] = tile[x][s_];
  }
}

// ---------------------------------------------------------------------------
// attended[t][b][c] = sum_s alpha[b][t][s] * ctx[s][b][c]; output bf16 for
// the MFMA output GEMM.
// ---------------------------------------------------------------------------
__global__ __launch_bounds__(256) void attend_kernel(
    const float* __restrict__ alpha_ws, const float* __restrict__ ctx,
    ushort* __restrict__ attb) {
  __shared__ float al[16][129];
  __shared__ float4 cx4[8][129];
  __shared__ float4 a4[16][129];
  const int tid = threadIdx.x;
  const int b = blockIdx.y;
  const int t0 = blockIdx.x << 4;

  for (int i = tid; i < 16 * 128; i += 256) {
    int r = i >> 7, s = i & 127;
    al[r][s] = alpha_ws[((size_t)b * T_DIM + t0 + r) * S_DIM + s];
  }
  const int tt = tid >> 4;
  const int cg = tid & 15;
  float4 acc[8];
#pragma unroll
  for (int jj = 0; jj < 8; ++jj) acc[jj] = make_float4(0.f, 0.f, 0.f, 0.f);

  for (int s0 = 0; s0 < S_DIM; s0 += 8) {
    __syncthreads();
    for (int i = tid; i < 8 * 128; i += 256) {
      int r = i >> 7, q = i & 127;
      cx4[r][q] = *(const float4*)(ctx + ((size_t)(s0 + r) * B_DIM + b) * C_DIM + (q << 2));
    }
    __syncthreads();
#pragma unroll
    for (int r = 0; r < 8; ++r) {
      const float a = al[tt][s0 + r];
#pragma unroll
      for (int jj = 0; jj < 8; ++jj) {
        const float4 c = cx4[r][cg + (jj << 4)];
        acc[jj].x += a * c.x; acc[jj].y += a * c.y;
        acc[jj].z += a * c.z; acc[jj].w += a * c.w;
      }
    }
  }
  __syncthreads();
#pragma unroll
  for (int jj = 0; jj < 8; ++jj) a4[tt][cg + (jj << 4)] = acc[jj];
  __syncthreads();
  for (int i = tid; i < 16 * 64; i += 256) {
    const int r = i >> 6, g = i & 63;
    const float4 lo = a4[r][g * 2], hi = a4[r][g * 2 + 1];
    uint4 o;
    o.x = bfpair(lo.x, lo.y); o.y = bfpair(lo.z, lo.w);
    o.z = bfpair(hi.x, hi.y); o.w = bfpair(hi.z, hi.w);
    *(uint4*)(attb + ((size_t)(t0 + r) * B_DIM + b) * C_DIM + g * 8) = o;
  }
}

// ---------------------------------------------------------------------------
extern "C" void kernel_launch(void* const* d_in, const int* in_sizes, int n_in,
                              void* d_out, int out_size, void* d_ws, size_t ws_size,
                              hipStream_t stream) {
  const float* hid       = (const float*)d_in[0];   // (T,B,H)
  const float* ctx       = (const float*)d_in[1];   // (S,B,C)
  const float* ctx_mask  = (const float*)d_in[2];   // (S,B)
  const float* W_hid2mid = (const float*)d_in[3];   // (M,H)
  const float* W_ctx2mid = (const float*)d_in[4];   // (M,C)
  const float* w_ff      = (const float*)d_in[5];   // (M,)
  const float* W_att2hid = (const float*)d_in[6];   // (H,C)
  float* out = (float*)d_out;
  float* ws  = (float*)d_ws;

  const int MEG = 1 << 20;
  // ws layout (floats), sequential-reuse safe:
  //   [0,1M)   EH        (T*B*M f32)      written k2, read k4
  //   [1M,2M)  EC        (S*B*M f32)      written k3, read k4
  //   [2M,3M)  HBF bf16  (hid, 2M elems)  written k1, read k2; then ATTBF (k6 w, k7 r)
  //   [3M,4M)  CBF bf16  (ctx, 2M elems)  written k1, read k3; then AWS f32 [3M,3.5M) (k4 w)
  //   [4M,..)  W bf16: WHBF 128K elems | WCBF 128K | WABF 256K   (high water ~17 MB)
  float* EH = ws;
  float* EC = ws + MEG;
  ushort* HBF = (ushort*)(ws + 2 * MEG);
  ushort* ATTBF = HBF;
  ushort* CBF = (ushort*)(ws + 3 * MEG);
  float* AWS = ws + 3 * MEG;
  ushort* WHBF = (ushort*)(ws + 4 * MEG);
  ushort* WCBF = WHBF + 131072;
  ushort* WABF = WCBF + 131072;
  float* alpha_out = out;                              // (T,S,B)
  float* z_out     = out + T_DIM * S_DIM * B_DIM;      // (T,B,H)

  dim3 blk(256);
  cvt_kernel<<<2304, blk, 0, stream>>>(hid, HBF, 262144, ctx, CBF, 262144,
                                       W_hid2mid, WHBF, 16384, W_ctx2mid, WCBF, 16384,
                                       W_att2hid, WABF, 32768);
  gemm_bf16_mfma<1><<<dim3(M_DIM / 64, (T_DIM * B_DIM) / 64), blk, 0, stream>>>(
      HBF, WHBF, EH, T_DIM * B_DIM, H_DIM, M_DIM);
  gemm_bf16_mfma<1><<<dim3(M_DIM / 64, (S_DIM * B_DIM) / 64), blk, 0, stream>>>(
      CBF, WCBF, EC, S_DIM * B_DIM, C_DIM, M_DIM);
  scores_kernel<<<dim3(T_DIM / 8, B_DIM), blk, 0, stream>>>(EH, EC, w_ff, ctx_mask, AWS);
  alpha_tr_kernel<<<dim3(T_DIM, S_DIM / 32), blk, 0, stream>>>(AWS, alpha_out);
  attend_kernel<<<dim3(T_DIM / 16, B_DIM), blk, 0, stream>>>(AWS, ctx, ATTBF);
  gemm_bf16_mfma<0><<<dim3(H_DIM / 64, (T_DIM * B_DIM) / 64), blk, 0, stream>>>(
      ATTBF, WABF, z_out, T_DIM * B_DIM, C_DIM, H_DIM);
}

// Round 3
// 86.745 us; speedup vs baseline: 1.9938x; 1.1240x over previous
//
#include <hip/hip_runtime.h>
#include <hip/hip_bf16.h>

#define T_DIM 128
#define S_DIM 128
#define B_DIM 32
#define H_DIM 512
#define C_DIM 512
#define M_DIM 256
#define NEG_BIG -1e8f
#define K2LOG2E 2.8853900817779268f   // 2*log2(e): exp(2x) = exp2(K*x)

typedef __attribute__((ext_vector_type(8))) short shortx8;   // 8 bf16
typedef __attribute__((ext_vector_type(4))) float floatx4;

// f32 -> bf16 RNE, packed pair
__device__ __forceinline__ unsigned bfpair(float a, float b) {
  unsigned ua = __builtin_bit_cast(unsigned, a); ua += 0x7fffu + ((ua >> 16) & 1u);
  unsigned ub = __builtin_bit_cast(unsigned, b); ub += 0x7fffu + ((ub >> 16) & 1u);
  return (ua >> 16) | (ub & 0xffff0000u);
}
__device__ __forceinline__ uint4 pack2(const float4& a, const float4& b) {
  uint4 o;
  o.x = bfpair(a.x, a.y); o.y = bfpair(a.z, a.w);
  o.z = bfpair(b.x, b.y); o.w = bfpair(b.z, b.w);
  return o;
}

// ---------------------------------------------------------------------------
// ctx (S,B,C) f32 -> ctxT (B,C,S) bf16.  Grid (C/128, S/32, B).
// ---------------------------------------------------------------------------
__global__ __launch_bounds__(256) void ctxt_kernel(
    const float* __restrict__ ctx, ushort* __restrict__ ctxT) {
  __shared__ float tile[32][132];    // row stride 528B: float4-aligned, odd-ish banks
  const int c0 = blockIdx.x << 7, s0 = blockIdx.y << 5, bb = blockIdx.z;
  const int tid = threadIdx.x;
#pragma unroll
  for (int i = 0; i < 4; ++i) {
    const int idx = tid + (i << 8);
    const int s = idx >> 5, q = idx & 31;
    *(float4*)&tile[s][q << 2] =
        *(const float4*)(ctx + ((size_t)(s0 + s) * B_DIM + bb) * C_DIM + c0 + (q << 2));
  }
  __syncthreads();
  const int c = tid >> 1, h = tid & 1;
  float v[16];
#pragma unroll
  for (int j = 0; j < 16; ++j) v[j] = tile[h * 16 + j][c];
  uint4 oa, ob;
  oa.x = bfpair(v[0], v[1]);  oa.y = bfpair(v[2], v[3]);
  oa.z = bfpair(v[4], v[5]);  oa.w = bfpair(v[6], v[7]);
  ob.x = bfpair(v[8], v[9]);  ob.y = bfpair(v[10], v[11]);
  ob.z = bfpair(v[12], v[13]); ob.w = bfpair(v[14], v[15]);
  ushort* dst = ctxT + ((size_t)bb * C_DIM + c0 + c) * S_DIM + s0 + h * 16;
  *(uint4*)dst = oa;
  *(uint4*)(dst + 8) = ob;
}

// ---------------------------------------------------------------------------
// Templated MFMA GEMM: Y[n][m] = sum_k X[n][k]*W[m][k], f32 out.
// XF32/WF32: operand stored f32 in global (converted to bf16 inline).
// EXPOUT: Y = exp2(K2LOG2E*acc). TWOSET: blockIdx.z in {0,1} picks operand set;
// else z is a batch index applied via element strides Xz/Wz/Yz.
// 64x64 tile, BK=64, 4 waves (2x2), 2x2 frags of 16x16x32, XOR-swizzled LDS,
// register-prefetch software pipeline (next tile's loads issued after barrier).
// ---------------------------------------------------------------------------
template <int XF32, int WF32, int EXPOUT, int TWOSET>
__global__ __launch_bounds__(256) void gemm64(
    const void* Xa_, const void* Wa_, float* Ya_,
    const void* Xb_, const void* Wb_, float* Yb_,
    const int K, const long Xz, const long Wz, const long Yrow, const long Yz) {
  __shared__ ushort Xs[4096];
  __shared__ ushort Ws[4096];
  const int tid = threadIdx.x;
  const int m0 = blockIdx.x << 6, n0 = blockIdx.y << 6;
  const int z = blockIdx.z;
  const void* Xp = (TWOSET && z) ? Xb_ : Xa_;
  const void* Wp = (TWOSET && z) ? Wb_ : Wa_;
  float* Yp = (TWOSET && z) ? Yb_ : Ya_;
  const size_t xoff = TWOSET ? 0 : (size_t)z * (size_t)Xz;
  const size_t woff = TWOSET ? 0 : (size_t)z * (size_t)Wz;
  const size_t yoff = TWOSET ? 0 : (size_t)z * (size_t)Yz;

  const int lane = tid & 63, wave = tid >> 6;
  const int wn = wave & 1, wm = wave >> 1;
  const int l15 = lane & 15, lhi = lane >> 4;
  const int lr = tid & 63, ls = tid >> 6;             // load row / 16-col segment
  const int slot0 = (((2 * ls) ^ (lr & 7)) << 4);
  const int slot1 = (((2 * ls + 1) ^ (lr & 7)) << 4);
  char* xrow = (char*)Xs + lr * 128;
  char* wrow = (char*)Ws + lr * 128;

  floatx4 acc[2][2];
#pragma unroll
  for (int i = 0; i < 2; ++i)
#pragma unroll
    for (int j = 0; j < 2; ++j) acc[i][j] = (floatx4){0.f, 0.f, 0.f, 0.f};

  float4 xf[4], wvf[4];
  uint4 xu[2], wu[2];

#define LOAD_X(K0)                                                              \
  if (XF32) {                                                                   \
    const float* p = (const float*)Xp + xoff + (size_t)(n0 + lr) * K + (K0) + (ls << 4); \
    xf[0] = ((const float4*)p)[0]; xf[1] = ((const float4*)p)[1];               \
    xf[2] = ((const float4*)p)[2]; xf[3] = ((const float4*)p)[3];               \
  } else {                                                                      \
    const ushort* p = (const ushort*)Xp + xoff + (size_t)(n0 + lr) * K + (K0) + (ls << 4); \
    xu[0] = ((const uint4*)p)[0]; xu[1] = ((const uint4*)p)[1];                 \
  }
#define LOAD_W(K0)                                                              \
  if (WF32) {                                                                   \
    const float* p = (const float*)Wp + woff + (size_t)(m0 + lr) * K + (K0) + (ls << 4); \
    wvf[0] = ((const float4*)p)[0]; wvf[1] = ((const float4*)p)[1];             \
    wvf[2] = ((const float4*)p)[2]; wvf[3] = ((const float4*)p)[3];             \
  } else {                                                                      \
    const ushort* p = (const ushort*)Wp + woff + (size_t)(m0 + lr) * K + (K0) + (ls << 4); \
    wu[0] = ((const uint4*)p)[0]; wu[1] = ((const uint4*)p)[1];                 \
  }

  LOAD_X(0)
  LOAD_W(0)

  for (int k0 = 0; k0 < K; k0 += 64) {
    __syncthreads();   // previous tile's readers done
    if (XF32) {
      *(uint4*)(xrow + slot0) = pack2(xf[0], xf[1]);
      *(uint4*)(xrow + slot1) = pack2(xf[2], xf[3]);
    } else {
      *(uint4*)(xrow + slot0) = xu[0];
      *(uint4*)(xrow + slot1) = xu[1];
    }
    if (WF32) {
      *(uint4*)(wrow + slot0) = pack2(wvf[0], wvf[1]);
      *(uint4*)(wrow + slot1) = pack2(wvf[2], wvf[3]);
    } else {
      *(uint4*)(wrow + slot0) = wu[0];
      *(uint4*)(wrow + slot1) = wu[1];
    }
    __syncthreads();
    const int kn = k0 + 64;
    if (kn < K) {      // issue next tile's loads; latency hides under MFMA
      LOAD_X(kn)
      LOAD_W(kn)
    }
#pragma unroll
    for (int ks = 0; ks < 2; ++ks) {
      const int slot = lhi + (ks << 2);
      shortx8 af[2], bf[2];
#pragma unroll
      for (int fi = 0; fi < 2; ++fi) {
        const int row = wn * 32 + fi * 16 + l15;
        af[fi] = *(const shortx8*)((const char*)Xs + row * 128 + ((slot ^ (row & 7)) << 4));
      }
#pragma unroll
      for (int fj = 0; fj < 2; ++fj) {
        const int col = wm * 32 + fj * 16 + l15;
        bf[fj] = *(const shortx8*)((const char*)Ws + col * 128 + ((slot ^ (col & 7)) << 4));
      }
#pragma unroll
      for (int fi = 0; fi < 2; ++fi)
#pragma unroll
        for (int fj = 0; fj < 2; ++fj)
          acc[fi][fj] = __builtin_amdgcn_mfma_f32_16x16x32_bf16(af[fi], bf[fj], acc[fi][fj], 0, 0, 0);
    }
  }
#undef LOAD_X
#undef LOAD_W

#pragma unroll
  for (int fi = 0; fi < 2; ++fi)
#pragma unroll
    for (int fj = 0; fj < 2; ++fj)
#pragma unroll
      for (int r = 0; r < 4; ++r) {
        const int row = n0 + wn * 32 + fi * 16 + lhi * 4 + r;
        const int col = m0 + wm * 32 + fj * 16 + l15;
        float v = acc[fi][fj][r];
        if (EXPOUT) v = __builtin_amdgcn_exp2f(K2LOG2E * v);
        Yp[(size_t)row * Yrow + yoff + col] = v;
      }
}

// ---------------------------------------------------------------------------
// Fused scores + softmax, exp-factored:
//   alpha(s) = softmax_s( -2 * sum_m w[m] * rcp(EH[t,b,m]*EC[s,b,m] + 1) )
// Block: 8 t-rows x full S, fixed b. Thread tile 2t x 2s. EC staged in
// double-buffered LDS chunks of 32 m; global loads for chunk c+1 issued before
// computing chunk c (one barrier per chunk). Writes b-major aws (B,T,S).
// ---------------------------------------------------------------------------
__global__ __launch_bounds__(256) void scores_kernel(
    const float* __restrict__ EH, const float* __restrict__ EC,
    const float* __restrict__ w_ff, const float* __restrict__ ctx_mask,
    float* __restrict__ aws) {
  __shared__ float4 ec[2][8][128];   // [buf][m-quad][s]
  __shared__ float4 eh[2][8][8];     // [buf][m-quad][t]
  __shared__ float4 wf[2][8];
  __shared__ float msk[S_DIM];
  const int tid = threadIdx.x;
  const int b = blockIdx.y;
  const int t0 = blockIdx.x << 3;
  const int tt = tid >> 6;   // wave: t rows 2tt, 2tt+1
  const int st = tid & 63;   // s = st, st+64

  if (tid < S_DIM) msk[tid] = ctx_mask[(size_t)tid * B_DIM + b];

  float4 rec[4], reh, rwf;
#define SLOAD(C)                                                                \
  {                                                                             \
    _Pragma("unroll")                                                           \
    for (int i = 0; i < 4; ++i) {                                               \
      const int idx = tid + (i << 8);                                           \
      const int s_ = idx >> 3, q_ = idx & 7;                                    \
      rec[i] = *(const float4*)(EC + ((size_t)s_ * B_DIM + b) * M_DIM + ((C) << 5) + (q_ << 2)); \
    }                                                                           \
    if (tid < 64)                                                               \
      reh = *(const float4*)(EH + ((size_t)(t0 + (tid >> 3)) * B_DIM + b) * M_DIM + ((C) << 5) + ((tid & 7) << 2)); \
    if (tid < 8) rwf = *(const float4*)(w_ff + ((C) << 5) + (tid << 2));        \
  }
#define SSTORE(BUF)                                                             \
  {                                                                             \
    _Pragma("unroll")                                                           \
    for (int i = 0; i < 4; ++i) {                                               \
      const int idx = tid + (i << 8);                                           \
      ec[BUF][idx & 7][idx >> 3] = rec[i];                                      \
    }                                                                           \
    if (tid < 64) eh[BUF][tid & 7][tid >> 3] = reh;                             \
    if (tid < 8) wf[BUF][tid] = rwf;                                            \
  }

  floatx4 acc[2][2];
#pragma unroll
  for (int i = 0; i < 2; ++i)
#pragma unroll
    for (int j = 0; j < 2; ++j) acc[i][j] = (floatx4){0.f, 0.f, 0.f, 0.f};

  SLOAD(0)
  SSTORE(0)
  __syncthreads();

  for (int c = 0; c < 8; ++c) {
    const int cur = c & 1;
    if (c < 7) SLOAD(c + 1)            // latency overlaps compute below
#pragma unroll
    for (int q = 0; q < 8; ++q) {
      const float4 w4 = wf[cur][q];
      const float4 e0 = eh[cur][q][2 * tt], e1 = eh[cur][q][2 * tt + 1];
      const float4 c0 = ec[cur][q][st],     c1 = ec[cur][q][st + 64];
#define ACC1(A, E, Cc)                                                 \
  A[0] += w4.x * __builtin_amdgcn_rcpf(E.x * Cc.x + 1.f);              \
  A[1] += w4.y * __builtin_amdgcn_rcpf(E.y * Cc.y + 1.f);              \
  A[2] += w4.z * __builtin_amdgcn_rcpf(E.z * Cc.z + 1.f);              \
  A[3] += w4.w * __builtin_amdgcn_rcpf(E.w * Cc.w + 1.f);
      ACC1(acc[0][0], e0, c0) ACC1(acc[0][1], e0, c1)
      ACC1(acc[1][0], e1, c0) ACC1(acc[1][1], e1, c1)
#undef ACC1
    }
    if (c < 7) {
      SSTORE(cur ^ 1)
      __syncthreads();
    }
  }
#undef SLOAD
#undef SSTORE

  const float mk0 = msk[st], mk1 = msk[st + 64];
  float sc[2][2];
#pragma unroll
  for (int ti = 0; ti < 2; ++ti) {
    const floatx4 a0 = acc[ti][0], a1 = acc[ti][1];
    sc[ti][0] = (mk0 > 0.f) ? -2.f * (a0[0] + a0[1] + a0[2] + a0[3]) : NEG_BIG;
    sc[ti][1] = (mk1 > 0.f) ? -2.f * (a1[0] + a1[1] + a1[2] + a1[3]) : NEG_BIG;
  }
#pragma unroll
  for (int ti = 0; ti < 2; ++ti) {
    float mx = fmaxf(sc[ti][0], sc[ti][1]);
#pragma unroll
    for (int off = 32; off > 0; off >>= 1) mx = fmaxf(mx, __shfl_xor(mx, off));
    const float e0 = __expf(sc[ti][0] - mx), e1 = __expf(sc[ti][1] - mx);
    float sum = e0 + e1;
#pragma unroll
    for (int off = 32; off > 0; off >>= 1) sum += __shfl_xor(sum, off);
    const float rinv = 1.f / sum;
    float* w = aws + ((size_t)b * T_DIM + t0 + 2 * tt + ti) * S_DIM;
    w[st] = e0 * rinv;
    w[st + 64] = e1 * rinv;
  }
}

// ---------------------------------------------------------------------------
// aws (B,T,S) -> out (T,S,B), 32x32 LDS tiles.
// ---------------------------------------------------------------------------
__global__ __launch_bounds__(256) void alpha_tr_kernel(
    const float* __restrict__ aws, float* __restrict__ aout) {
  __shared__ float tile[32][33];
  const int t = blockIdx.x;
  const int s0 = blockIdx.y * 32;
  const int x = threadIdx.x & 31, y = threadIdx.x >> 5;
#pragma unroll
  for (int i = 0; i < 4; ++i) {
    const int b_ = i * 8 + y;
    tile[b_][x] = aws[((size_t)b_ * T_DIM + t) * S_DIM + s0 + x];
  }
  __syncthreads();
#pragma unroll
  for (int i = 0; i < 4; ++i) {
    const int s_ = i * 8 + y;
    aout[((size_t)t * S_DIM + s0 + s_) * B_DIM + x] = tile[x][s_];
  }
}

// ---------------------------------------------------------------------------
extern "C" void kernel_launch(void* const* d_in, const int* in_sizes, int n_in,
                              void* d_out, int out_size, void* d_ws, size_t ws_size,
                              hipStream_t stream) {
  const float* hid       = (const float*)d_in[0];   // (T,B,H)
  const float* ctx       = (const float*)d_in[1];   // (S,B,C)
  const float* ctx_mask  = (const float*)d_in[2];   // (S,B)
  const float* W_hid2mid = (const float*)d_in[3];   // (M,H)
  const float* W_ctx2mid = (const float*)d_in[4];   // (M,C)
  const float* w_ff      = (const float*)d_in[5];   // (M,)
  const float* W_att2hid = (const float*)d_in[6];   // (H,C)
  float* out = (float*)d_out;
  float* ws  = (float*)d_ws;

  const int MEG = 1 << 20;
  float*  EH   = ws;                          // (T*B, M) f32
  float*  EC   = ws + MEG;                    // (S*B, M) f32
  float*  AWS  = ws + 2 * MEG;                // (B,T,S) f32
  float*  ATT  = ws + 3 * MEG;                // (T,B,C) f32
  ushort* CTXT = (ushort*)(ws + 5 * MEG);     // (B,C,S) bf16
  float* alpha_out = out;                               // (T,S,B)
  float* z_out     = out + T_DIM * S_DIM * B_DIM;       // (T,B,H)

  dim3 blk(256);
  // ctx transpose -> bf16 (B,C,S)
  ctxt_kernel<<<dim3(C_DIM / 128, S_DIM / 32, B_DIM), blk, 0, stream>>>(ctx, CTXT);
  // EH = exp(2*hid.Wh^T), EC = exp(2*ctx.Wc^T)  (one launch, z picks set)
  gemm64<1, 1, 1, 1><<<dim3(M_DIM / 64, (T_DIM * B_DIM) / 64, 2), blk, 0, stream>>>(
      hid, W_hid2mid, EH, ctx, W_ctx2mid, EC, H_DIM, 0, 0, M_DIM, 0);
  // fused tanh-scores + masked softmax -> aws (B,T,S)
  scores_kernel<<<dim3(T_DIM / 8, B_DIM), blk, 0, stream>>>(EH, EC, w_ff, ctx_mask, AWS);
  // alpha output (T,S,B)
  alpha_tr_kernel<<<dim3(T_DIM, S_DIM / 32), blk, 0, stream>>>(AWS, alpha_out);
  // attended (T,B,C) = alpha_b (T,S) . ctxT_b (C,S)^T, batched over b
  gemm64<1, 0, 0, 0><<<dim3(C_DIM / 64, T_DIM / 64, B_DIM), blk, 0, stream>>>(
      AWS, CTXT, ATT, nullptr, nullptr, nullptr, S_DIM,
      (long)T_DIM * S_DIM, (long)C_DIM * S_DIM, (long)B_DIM * C_DIM, (long)C_DIM);
  // z (T,B,H) = att (T*B, C) . W_att2hid^T
  gemm64<1, 1, 0, 0><<<dim3(H_DIM / 64, (T_DIM * B_DIM) / 64, 1), blk, 0, stream>>>(
      ATT, W_att2hid, z_out, nullptr, nullptr, nullptr, C_DIM, 0, 0, H_DIM, 0);
}

// Round 4
// 80.340 us; speedup vs baseline: 2.1528x; 1.0797x over previous
//
#include <hip/hip_runtime.h>
#include <hip/hip_bf16.h>

#define T_DIM 128
#define S_DIM 128
#define B_DIM 32
#define H_DIM 512
#define C_DIM 512
#define M_DIM 256
#define NEG_BIG -1e8f
#define K2LOG2E 2.8853900817779268f   // 2*log2(e): exp(2x) = exp2(K*x)

typedef __attribute__((ext_vector_type(8))) short shortx8;   // 8 bf16
typedef __attribute__((ext_vector_type(4))) float floatx4;

// f32 -> bf16 RNE, packed pair
__device__ __forceinline__ unsigned bfpair(float a, float b) {
  unsigned ua = __builtin_bit_cast(unsigned, a); ua += 0x7fffu + ((ua >> 16) & 1u);
  unsigned ub = __builtin_bit_cast(unsigned, b); ub += 0x7fffu + ((ub >> 16) & 1u);
  return (ua >> 16) | (ub & 0xffff0000u);
}
__device__ __forceinline__ uint4 pack2(const float4& a, const float4& b) {
  uint4 o;
  o.x = bfpair(a.x, a.y); o.y = bfpair(a.z, a.w);
  o.z = bfpair(b.x, b.y); o.w = bfpair(b.z, b.w);
  return o;
}

// ---------------------------------------------------------------------------
// Shared MFMA GEMM core: Y(n,m) = sum_k X[n][k]*W[m][k], f32 operands
// converted to bf16 inline during LDS staging. 64x64 tile, BK=64, 4 waves
// (2x2), 2x2 frags of 16x16x32, XOR-swizzled LDS, register-prefetch pipeline.
// xptr/wptr: per-thread row pointers (already offset by (n0+lr)*xrs + ls*16).
// ---------------------------------------------------------------------------
__device__ __forceinline__ void gemm_core_f32(
    const float* __restrict__ xptr, const float* __restrict__ wptr, int nk,
    ushort* Xs, ushort* Ws, int tid, floatx4 acc[2][2]) {
  const int lane = tid & 63, wave = tid >> 6;
  const int wn = wave & 1, wm = wave >> 1;
  const int l15 = lane & 15, lhi = lane >> 4;
  const int lr = tid & 63, ls = tid >> 6;
  const int slot0 = (((2 * ls) ^ (lr & 7)) << 4);
  const int slot1 = (((2 * ls + 1) ^ (lr & 7)) << 4);
  char* xrow = (char*)Xs + lr * 128;
  char* wrow = (char*)Ws + lr * 128;

  float4 xf[4], wf[4];
#define LOADXW                                                   \
  xf[0] = ((const float4*)xptr)[0]; xf[1] = ((const float4*)xptr)[1]; \
  xf[2] = ((const float4*)xptr)[2]; xf[3] = ((const float4*)xptr)[3]; \
  wf[0] = ((const float4*)wptr)[0]; wf[1] = ((const float4*)wptr)[1]; \
  wf[2] = ((const float4*)wptr)[2]; wf[3] = ((const float4*)wptr)[3];
  LOADXW
  for (int it = 0; it < nk; ++it) {
    __syncthreads();   // previous tile's readers done
    *(uint4*)(xrow + slot0) = pack2(xf[0], xf[1]);
    *(uint4*)(xrow + slot1) = pack2(xf[2], xf[3]);
    *(uint4*)(wrow + slot0) = pack2(wf[0], wf[1]);
    *(uint4*)(wrow + slot1) = pack2(wf[2], wf[3]);
    __syncthreads();
    if (it + 1 < nk) {   // issue next tile's loads; latency hides under MFMA
      xptr += 64; wptr += 64;
      LOADXW
    }
#pragma unroll
    for (int ks = 0; ks < 2; ++ks) {
      const int slot = lhi + (ks << 2);
      shortx8 af[2], bfr[2];
#pragma unroll
      for (int fi = 0; fi < 2; ++fi) {
        const int row = wn * 32 + fi * 16 + l15;
        af[fi] = *(const shortx8*)((const char*)Xs + row * 128 + ((slot ^ (row & 7)) << 4));
      }
#pragma unroll
      for (int fj = 0; fj < 2; ++fj) {
        const int col = wm * 32 + fj * 16 + l15;
        bfr[fj] = *(const shortx8*)((const char*)Ws + col * 128 + ((slot ^ (col & 7)) << 4));
      }
#pragma unroll
      for (int fi = 0; fi < 2; ++fi)
#pragma unroll
        for (int fj = 0; fj < 2; ++fj)
          acc[fi][fj] = __builtin_amdgcn_mfma_f32_16x16x32_bf16(af[fi], bfr[fj], acc[fi][fj], 0, 0, 0);
    }
  }
#undef LOADXW
}

// ---------------------------------------------------------------------------
// One launch, three GEMM sets (all K=512, f32 in, f32 out):
//   bid [0,256):    EH (T*B,M) = exp(2 * hid . Wh^T)     n-tiles 64, m-tiles 4
//   bid [256,512):  EC (S*B,M) = exp(2 * ctx . Wc^T)     n-tiles 64, m-tiles 4
//   bid [512,1024): CW (B,H,S) = Wa . ctx_b^T  (batched) n=h (8), m=s (2), b=32
// ---------------------------------------------------------------------------
__global__ __launch_bounds__(256) void gemm_multi(
    const float* __restrict__ hid, const float* __restrict__ Wh, float* __restrict__ EH,
    const float* __restrict__ ctx, const float* __restrict__ Wc, float* __restrict__ EC,
    const float* __restrict__ Wa, float* __restrict__ CW) {
  __shared__ ushort Xs[4096];
  __shared__ ushort Ws[4096];
  const int tid = threadIdx.x;
  const int bid = blockIdx.x;
  const int lr = tid & 63, ls = tid >> 6;

  const float *X, *W;
  float* Y;
  long xrs, wrs;
  int n0, m0, yrow;
  size_t yoff;
  bool expo;
  if (bid < 512) {
    const int lb = bid & 255;
    n0 = (lb >> 2) << 6; m0 = (lb & 3) << 6;
    X = (bid < 256) ? hid : ctx;
    W = (bid < 256) ? Wh : Wc;
    Y = (bid < 256) ? EH : EC;
    xrs = 512; wrs = 512; yrow = M_DIM; yoff = 0; expo = true;
  } else {
    const int lb = bid - 512;
    const int b = lb >> 4, loc = lb & 15;
    n0 = (loc >> 1) << 6;            // h tile
    m0 = (loc & 1) << 6;             // s tile
    X = Wa; xrs = 512;
    W = ctx + (size_t)b * C_DIM; wrs = (long)B_DIM * C_DIM;
    Y = CW; yrow = S_DIM; yoff = (size_t)b * H_DIM * S_DIM; expo = false;
  }

  floatx4 acc[2][2];
#pragma unroll
  for (int i = 0; i < 2; ++i)
#pragma unroll
    for (int j = 0; j < 2; ++j) acc[i][j] = (floatx4){0.f, 0.f, 0.f, 0.f};

  const float* xptr = X + (size_t)(n0 + lr) * xrs + (ls << 4);
  const float* wptr = W + (size_t)(m0 + lr) * wrs + (ls << 4);
  gemm_core_f32(xptr, wptr, 512 / 64, Xs, Ws, tid, acc);

  const int lane = tid & 63, wave = tid >> 6;
  const int wn = wave & 1, wm = wave >> 1;
  const int l15 = lane & 15, lhi = lane >> 4;
#pragma unroll
  for (int fi = 0; fi < 2; ++fi)
#pragma unroll
    for (int fj = 0; fj < 2; ++fj)
#pragma unroll
      for (int r = 0; r < 4; ++r) {
        const int row = n0 + wn * 32 + fi * 16 + lhi * 4 + r;
        const int col = m0 + wm * 32 + fj * 16 + l15;
        float v = acc[fi][fj][r];
        if (expo) v = __builtin_amdgcn_exp2f(K2LOG2E * v);
        Y[(size_t)row * yrow + yoff + col] = v;
      }
}

// ---------------------------------------------------------------------------
// z (T,B,H) = alpha_b (T,S) . CW_b (H,S)^T, batched over b. K = S = 128.
// ---------------------------------------------------------------------------
__global__ __launch_bounds__(256) void zgemm_kernel(
    const float* __restrict__ AWS, const float* __restrict__ CW,
    float* __restrict__ z) {
  __shared__ ushort Xs[4096];
  __shared__ ushort Ws[4096];
  const int tid = threadIdx.x;
  const int m0 = blockIdx.x << 6;          // h
  const int n0 = blockIdx.y << 6;          // t
  const int b = blockIdx.z;
  const int lr = tid & 63, ls = tid >> 6;

  floatx4 acc[2][2];
#pragma unroll
  for (int i = 0; i < 2; ++i)
#pragma unroll
    for (int j = 0; j < 2; ++j) acc[i][j] = (floatx4){0.f, 0.f, 0.f, 0.f};

  const float* xptr = AWS + (size_t)b * T_DIM * S_DIM + (size_t)(n0 + lr) * S_DIM + (ls << 4);
  const float* wptr = CW + (size_t)b * H_DIM * S_DIM + (size_t)(m0 + lr) * S_DIM + (ls << 4);
  gemm_core_f32(xptr, wptr, 128 / 64, Xs, Ws, tid, acc);

  const int lane = tid & 63, wave = tid >> 6;
  const int wn = wave & 1, wm = wave >> 1;
  const int l15 = lane & 15, lhi = lane >> 4;
#pragma unroll
  for (int fi = 0; fi < 2; ++fi)
#pragma unroll
    for (int fj = 0; fj < 2; ++fj)
#pragma unroll
      for (int r = 0; r < 4; ++r) {
        const int row = n0 + wn * 32 + fi * 16 + lhi * 4 + r;   // t
        const int col = m0 + wm * 32 + fj * 16 + l15;           // h
        z[((size_t)row * B_DIM + b) * H_DIM + col] = acc[fi][fj][r];
      }
}

// ---------------------------------------------------------------------------
// Fused scores + softmax, exp-factored:
//   alpha(s) = softmax_s( -2 * sum_m w[m] * rcp(EH[t,b,m]*EC[s,b,m] + 1) )
// Block: 8 t-rows x full S, fixed b. Thread tile 2t x 2s. Double-buffered
// 32-m chunks, one barrier per chunk. Writes b-major aws (B,T,S).
// ---------------------------------------------------------------------------
__global__ __launch_bounds__(256) void scores_kernel(
    const float* __restrict__ EH, const float* __restrict__ EC,
    const float* __restrict__ w_ff, const float* __restrict__ ctx_mask,
    float* __restrict__ aws) {
  __shared__ float4 ec[2][8][128];
  __shared__ float4 eh[2][8][8];
  __shared__ float4 wf[2][8];
  __shared__ float msk[S_DIM];
  const int tid = threadIdx.x;
  const int b = blockIdx.y;
  const int t0 = blockIdx.x << 3;
  const int tt = tid >> 6;
  const int st = tid & 63;

  if (tid < S_DIM) msk[tid] = ctx_mask[(size_t)tid * B_DIM + b];

  float4 rec[4], reh, rwf;
#define SLOAD(C)                                                                \
  {                                                                             \
    _Pragma("unroll")                                                           \
    for (int i = 0; i < 4; ++i) {                                               \
      const int idx = tid + (i << 8);                                           \
      const int s_ = idx >> 3, q_ = idx & 7;                                    \
      rec[i] = *(const float4*)(EC + ((size_t)s_ * B_DIM + b) * M_DIM + ((C) << 5) + (q_ << 2)); \
    }                                                                           \
    if (tid < 64)                                                               \
      reh = *(const float4*)(EH + ((size_t)(t0 + (tid >> 3)) * B_DIM + b) * M_DIM + ((C) << 5) + ((tid & 7) << 2)); \
    if (tid < 8) rwf = *(const float4*)(w_ff + ((C) << 5) + (tid << 2));        \
  }
#define SSTORE(BUF)                                                             \
  {                                                                             \
    _Pragma("unroll")                                                           \
    for (int i = 0; i < 4; ++i) {                                               \
      const int idx = tid + (i << 8);                                           \
      ec[BUF][idx & 7][idx >> 3] = rec[i];                                      \
    }                                                                           \
    if (tid < 64) eh[BUF][tid & 7][tid >> 3] = reh;                             \
    if (tid < 8) wf[BUF][tid] = rwf;                                            \
  }

  floatx4 acc[2][2];
#pragma unroll
  for (int i = 0; i < 2; ++i)
#pragma unroll
    for (int j = 0; j < 2; ++j) acc[i][j] = (floatx4){0.f, 0.f, 0.f, 0.f};

  SLOAD(0)
  SSTORE(0)
  __syncthreads();

  for (int c = 0; c < 8; ++c) {
    const int cur = c & 1;
    if (c < 7) SLOAD(c + 1)
#pragma unroll
    for (int q = 0; q < 8; ++q) {
      const float4 w4 = wf[cur][q];
      const float4 e0 = eh[cur][q][2 * tt], e1 = eh[cur][q][2 * tt + 1];
      const float4 c0 = ec[cur][q][st],     c1 = ec[cur][q][st + 64];
#define ACC1(A, E, Cc)                                                 \
  A[0] += w4.x * __builtin_amdgcn_rcpf(E.x * Cc.x + 1.f);              \
  A[1] += w4.y * __builtin_amdgcn_rcpf(E.y * Cc.y + 1.f);              \
  A[2] += w4.z * __builtin_amdgcn_rcpf(E.z * Cc.z + 1.f);              \
  A[3] += w4.w * __builtin_amdgcn_rcpf(E.w * Cc.w + 1.f);
      ACC1(acc[0][0], e0, c0) ACC1(acc[0][1], e0, c1)
      ACC1(acc[1][0], e1, c0) ACC1(acc[1][1], e1, c1)
#undef ACC1
    }
    if (c < 7) {
      SSTORE(cur ^ 1)
      __syncthreads();
    }
  }
#undef SLOAD
#undef SSTORE

  const float mk0 = msk[st], mk1 = msk[st + 64];
  float sc[2][2];
#pragma unroll
  for (int ti = 0; ti < 2; ++ti) {
    const floatx4 a0 = acc[ti][0], a1 = acc[ti][1];
    sc[ti][0] = (mk0 > 0.f) ? -2.f * (a0[0] + a0[1] + a0[2] + a0[3]) : NEG_BIG;
    sc[ti][1] = (mk1 > 0.f) ? -2.f * (a1[0] + a1[1] + a1[2] + a1[3]) : NEG_BIG;
  }
#pragma unroll
  for (int ti = 0; ti < 2; ++ti) {
    float mx = fmaxf(sc[ti][0], sc[ti][1]);
#pragma unroll
    for (int off = 32; off > 0; off >>= 1) mx = fmaxf(mx, __shfl_xor(mx, off));
    const float e0 = __expf(sc[ti][0] - mx), e1 = __expf(sc[ti][1] - mx);
    float sum = e0 + e1;
#pragma unroll
    for (int off = 32; off > 0; off >>= 1) sum += __shfl_xor(sum, off);
    const float rinv = 1.f / sum;
    float* w = aws + ((size_t)b * T_DIM + t0 + 2 * tt + ti) * S_DIM;
    w[st] = e0 * rinv;
    w[st + 64] = e1 * rinv;
  }
}

// ---------------------------------------------------------------------------
// aws (B,T,S) -> out (T,S,B), 32x32 LDS tiles.
// ---------------------------------------------------------------------------
__global__ __launch_bounds__(256) void alpha_tr_kernel(
    const float* __restrict__ aws, float* __restrict__ aout) {
  __shared__ float tile[32][33];
  const int t = blockIdx.x;
  const int s0 = blockIdx.y * 32;
  const int x = threadIdx.x & 31, y = threadIdx.x >> 5;
#pragma unroll
  for (int i = 0; i < 4; ++i) {
    const int b_ = i * 8 + y;
    tile[b_][x] = aws[((size_t)b_ * T_DIM + t) * S_DIM + s0 + x];
  }
  __syncthreads();
#pragma unroll
  for (int i = 0; i < 4; ++i) {
    const int s_ = i * 8 + y;
    aout[((size_t)t * S_DIM + s0 + s_) * B_DIM + x] = tile[x][s_];
  }
}

// ---------------------------------------------------------------------------
extern "C" void kernel_launch(void* const* d_in, const int* in_sizes, int n_in,
                              void* d_out, int out_size, void* d_ws, size_t ws_size,
                              hipStream_t stream) {
  const float* hid       = (const float*)d_in[0];   // (T,B,H)
  const float* ctx       = (const float*)d_in[1];   // (S,B,C)
  const float* ctx_mask  = (const float*)d_in[2];   // (S,B)
  const float* W_hid2mid = (const float*)d_in[3];   // (M,H)
  const float* W_ctx2mid = (const float*)d_in[4];   // (M,C)
  const float* w_ff      = (const float*)d_in[5];   // (M,)
  const float* W_att2hid = (const float*)d_in[6];   // (H,C)
  float* out = (float*)d_out;
  float* ws  = (float*)d_ws;

  const int MEG = 1 << 20;
  float* EH  = ws;                  // (T*B, M) f32   1M
  float* EC  = ws + MEG;            // (S*B, M) f32   1M
  float* AWS = ws + 2 * MEG;        // (B,T,S)  f32   0.5M
  float* CW  = ws + 3 * MEG;        // (B,H,S)  f32   2M
  float* alpha_out = out;                               // (T,S,B)
  float* z_out     = out + T_DIM * S_DIM * B_DIM;       // (T,B,H)

  dim3 blk(256);
  // EH = exp(2*hid.Wh^T), EC = exp(2*ctx.Wc^T), CW_b = Wa.ctx_b^T  (one launch)
  gemm_multi<<<1024, blk, 0, stream>>>(hid, W_hid2mid, EH, ctx, W_ctx2mid, EC,
                                       W_att2hid, CW);
  // fused tanh-scores + masked softmax -> aws (B,T,S)
  scores_kernel<<<dim3(T_DIM / 8, B_DIM), blk, 0, stream>>>(EH, EC, w_ff, ctx_mask, AWS);
  // alpha output (T,S,B)
  alpha_tr_kernel<<<dim3(T_DIM, S_DIM / 32), blk, 0, stream>>>(AWS, alpha_out);
  // z (T,B,H) = alpha_b . CW_b^T
  zgemm_kernel<<<dim3(H_DIM / 64, T_DIM / 64, B_DIM), blk, 0, stream>>>(AWS, CW, z_out);
}